// Round 1
// 91.462 us; speedup vs baseline: 1.0339x; 1.0339x over previous
//
#include <hip/hip_runtime.h>

// HEGN loss: L_reg + bidirectional chamfer(x, y).  B=8, N=M=4096.
#define BB 8
#define NN 4096
#define MC 256                    // reference points staged per chunk
#define NCHUNK (NN / MC)          // 16
#define KPT 4                     // query points per thread (4 -> 1024 blocks, 4 waves/SIMD)
#define TPB 256
#define PTS_PER_BLOCK (TPB * KPT) // 1024
#define NPTS (2 * BB * NN)        // 65536 (both directions)

// ws layout: partial[c][zb][p]  c in [0,16), zb in [0,16), p in [0,4096) -> 4 MB

__global__ __launch_bounds__(TPB) void chamfer_partial(
    const float* __restrict__ X, const float* __restrict__ Y,
    float* __restrict__ partial, float* __restrict__ out) {
  __shared__ float4 ly[MC];       // (-2*y0, -2*y1, -2*y2, |y|^2)
  const int tid = threadIdx.x;
  const int zb  = blockIdx.z;     // (dir<<3) | b
  const int b   = zb & (BB - 1);
  const int dir = zb >> 3;
  const float* pts  = dir ? (Y + b * NN * 3) : (X + b * NN * 3);
  const float* refs = dir ? (X + b * NN * 3) : (Y + b * NN * 3);
  const int c = blockIdx.y;

  // Replaces the 4-byte hipMemsetAsync dispatch. Safe: chamfer_reduce only
  // touches out after this kernel fully completes (stream ordering).
  if (tid == 0 && blockIdx.x == 0 && blockIdx.y == 0 && blockIdx.z == 0)
    *out = 0.0f;

  {
    const int j = c * MC + tid;   // MC == TPB: one staging iteration
    const float a0 = refs[j * 3 + 0];
    const float a1 = refs[j * 3 + 1];
    const float a2 = refs[j * 3 + 2];
    ly[tid] = make_float4(-2.0f * a0, -2.0f * a1, -2.0f * a2,
                          a0 * a0 + a1 * a1 + a2 * a2);
  }
  __syncthreads();

  float px[KPT], py[KPT], pz[KPT], m[KPT];
  const int p0 = blockIdx.x * PTS_PER_BLOCK + tid;
#pragma unroll
  for (int k = 0; k < KPT; k++) {
    const int p = p0 + k * TPB;
    px[k] = pts[p * 3 + 0];
    py[k] = pts[p * 3 + 1];
    pz[k] = pts[p * 3 + 2];
    m[k] = 1e30f;
  }

  // min over chunk of (|y|^2 - 2 x.y); |x|^2 added after the loop.
  // 4-ref body, with next body's LDS reads issued one body ahead so the
  // lgkmcnt wait lands ~120cy after issue instead of immediately before use.
#define CHAMFER_BODY(w0, w1, w2, w3)                                           \
  _Pragma("unroll") for (int k = 0; k < KPT; k++) {                            \
    const float s0 =                                                           \
        fmaf(px[k], w0.x, fmaf(py[k], w0.y, fmaf(pz[k], w0.z, w0.w)));         \
    const float s1 =                                                           \
        fmaf(px[k], w1.x, fmaf(py[k], w1.y, fmaf(pz[k], w1.z, w1.w)));         \
    const float s2 =                                                           \
        fmaf(px[k], w2.x, fmaf(py[k], w2.y, fmaf(pz[k], w2.z, w2.w)));         \
    const float s3 =                                                           \
        fmaf(px[k], w3.x, fmaf(py[k], w3.y, fmaf(pz[k], w3.z, w3.w)));         \
    m[k] = fminf(m[k], fminf(fminf(s0, s1), fminf(s2, s3)));                   \
  }

  float4 w0 = ly[0], w1 = ly[1], w2 = ly[2], w3 = ly[3];
#pragma unroll 2
  for (int j = 0; j < MC - 4; j += 4) {
    const float4 n0 = ly[j + 4];
    const float4 n1 = ly[j + 5];
    const float4 n2 = ly[j + 6];
    const float4 n3 = ly[j + 7];
    CHAMFER_BODY(w0, w1, w2, w3)
    w0 = n0; w1 = n1; w2 = n2; w3 = n3;
  }
  CHAMFER_BODY(w0, w1, w2, w3)
#undef CHAMFER_BODY

#pragma unroll
  for (int k = 0; k < KPT; k++) {
    const int p = p0 + k * TPB;
    const float pn = px[k] * px[k] + py[k] * py[k] + pz[k] * pz[k];
    partial[(c * (2 * BB) + zb) * NN + p] = m[k] + pn;
  }
}

// Min across chunks, block-sum, 1 atomic per block into out (zeroed by
// chamfer_partial). Block 0 also adds L_reg. 256 blocks x 1 q/thread:
// all 16 chunk loads independent -> latency-bound time minimized.
__global__ __launch_bounds__(256) void chamfer_reduce(
    const float* __restrict__ partial,
    const float* __restrict__ R, const float* __restrict__ S,
    const float* __restrict__ t, const float* __restrict__ Rgt,
    const float* __restrict__ Sgt, const float* __restrict__ tgt,
    float* __restrict__ out) {
  const int tid = threadIdx.x;
  const int q = blockIdx.x * 256 + tid;   // 256 blocks cover NPTS
  float m = 1e30f;
#pragma unroll
  for (int c = 0; c < NCHUNK; c++)
    m = fminf(m, partial[c * NPTS + q]);
  float s = m;
  for (int o = 32; o > 0; o >>= 1) s += __shfl_down(s, o);
  __shared__ float wsum[4];
  if ((tid & 63) == 0) wsum[tid >> 6] = s;
  __syncthreads();
  if (tid == 0) {
    const float bs = wsum[0] + wsum[1] + wsum[2] + wsum[3];
    atomicAdd(out, bs * (1.0f / (float)(BB * NN)));
  }

  if (blockIdx.x == 0) {
    float v = 0.0f;
    if (tid < 72) {                       // R @ R_gt^T - I, squared
      const int b = tid / 9, ik = tid % 9, i = ik / 3, k = ik % 3;
      const float* Rb = R + b * 9;
      const float* Gb = Rgt + b * 9;
      float d = Rb[i * 3 + 0] * Gb[k * 3 + 0] +
                Rb[i * 3 + 1] * Gb[k * 3 + 1] +
                Rb[i * 3 + 2] * Gb[k * 3 + 2];
      d -= (i == k) ? 1.0f : 0.0f;
      v = d * d;
    } else if (tid < 96) {                // (S - S_gt)^2
      const int i = tid - 72;
      const float d = S[i] - Sgt[i];
      v = d * d;
    } else if (tid < 120) {               // (t - t_gt)^2
      const int i = tid - 96;
      const float d = t[i] - tgt[i];
      v = d * d;
    }
    for (int o = 32; o > 0; o >>= 1) v += __shfl_down(v, o);
    __shared__ float rsum[4];
    if ((tid & 63) == 0) rsum[tid >> 6] = v;
    __syncthreads();
    if (tid == 0) atomicAdd(out, rsum[0] + rsum[1] + rsum[2] + rsum[3]);
  }
}

extern "C" void kernel_launch(void* const* d_in, const int* in_sizes, int n_in,
                              void* d_out, int out_size, void* d_ws, size_t ws_size,
                              hipStream_t stream) {
  const float* X   = (const float*)d_in[0];
  const float* Y   = (const float*)d_in[1];
  const float* R   = (const float*)d_in[2];
  const float* S   = (const float*)d_in[3];
  const float* t   = (const float*)d_in[4];
  const float* Rgt = (const float*)d_in[5];
  const float* Sgt = (const float*)d_in[6];
  const float* tgt = (const float*)d_in[7];

  float* partial = (float*)d_ws;
  float* out     = (float*)d_out;

  dim3 gA(NN / PTS_PER_BLOCK, NCHUNK, 2 * BB);   // (4, 16, 16) = 1024 blocks
  chamfer_partial<<<gA, TPB, 0, stream>>>(X, Y, partial, out);

  chamfer_reduce<<<NPTS / 256, 256, 0, stream>>>(partial, R, S, t, Rgt, Sgt, tgt, out);
}